// Round 3
// baseline (341.206 us; speedup 1.0000x reference)
//
#include <hip/hip_runtime.h>

#define E_EDGES 1000000
#define BM 64
#define NBLK (E_EDGES / BM)   // 15625
#define DIN 288
#define PADA 296              // bf16 elems; row stride 592 B (8/16B aligned)
#define H1DIM 128
#define PAD1 136              // 272 B row stride, 16B-aligned for v8bf reads
#define H2DIM 64
#define PAD2 68               // scalar access only

typedef __bf16 v8bf __attribute__((ext_vector_type(8)));
typedef __bf16 v4bf __attribute__((ext_vector_type(4)));
typedef float  v4f  __attribute__((ext_vector_type(4)));

__device__ __forceinline__ void cvt_store4(__bf16* p, float4 v) {
    v4bf o;
    o[0] = (__bf16)v.x; o[1] = (__bf16)v.y; o[2] = (__bf16)v.z; o[3] = (__bf16)v.w;
    *(v4bf*)p = o;      // 8B store, p always 8B-aligned
}

// Transpose+convert W1 f32 [288,128] -> wt1 bf16 [128][288], W2 f32 [128,64] -> wt2 bf16 [64][128]
__global__ void prep_kernel(const float* __restrict__ W1, const float* __restrict__ W2,
                            __bf16* __restrict__ wt1, __bf16* __restrict__ wt2) {
    int i = blockIdx.x * 256 + threadIdx.x;
    if (i < DIN * H1DIM) {              // 36864
        int n = i / DIN, k = i - n * DIN;
        wt1[i] = (__bf16)W1[k * H1DIM + n];
    }
    if (i < H1DIM * H2DIM) {            // 8192
        int n = i / H1DIM, k = i - n * H1DIM;
        wt2[i] = (__bf16)W2[k * H2DIM + n];
    }
}

__global__ __launch_bounds__(256, 2) void fused_kernel(
    const float* __restrict__ z, const int* __restrict__ eidx,
    const int* __restrict__ bt, const float* __restrict__ embed,
    const float* __restrict__ b1, const float* __restrict__ b2,
    const float* __restrict__ W3, const float* __restrict__ b3,
    const __bf16* __restrict__ wt1, const __bf16* __restrict__ wt2,
    float* __restrict__ out)
{
    // static LDS: 37888 + 17408 + 8704 + 512 + 256 + 256 + 4 = 65028 B (<= 65536)
    __shared__ __bf16 sA[BM * PADA];
    __shared__ __bf16 sH1[BM * PAD1];
    __shared__ __bf16 sH2[BM * PAD2];
    __shared__ float sb1[H1DIM];
    __shared__ float sb2[H2DIM];
    __shared__ float sw3[H2DIM];
    __shared__ float sb3;

    const int tid = threadIdx.x;
    const int e0 = blockIdx.x * BM;

    // ---- stage biases / W3 (exact f32) ----
    if (tid < 128) {
        sb1[tid] = b1[tid];
    } else if (tid < 192) {
        sb2[tid - 128] = b2[tid - 128];
    } else {
        int k = tid - 192;
        sw3[k] = W3[k];
        if (k == 0) sb3 = b3[0];
    }

    // ---- gather + f32->bf16 convert: 64 rows x 288 f32 = 72 float4-chunks/row ----
    {
        const int r = tid >> 2;         // edge row 0..63
        const int j = tid & 3;          // sub-lane 0..3
        const int e = e0 + r;
        const int isrc = eidx[e];
        const int idst = eidx[E_EDGES + e];
        const int ib   = bt[e];
        const float4* zsrc = (const float4*)(z + (size_t)isrc * 128);
        const float4* zdst = (const float4*)(z + (size_t)idst * 128);
        const float4* emb  = (const float4*)(embed + (size_t)ib * 32);
        __bf16* rowp = &sA[r * PADA];
        #pragma unroll
        for (int i = 0; i < 8; ++i) {
            int p = i * 4 + j;                  // 0..31
            cvt_store4(rowp + p * 4, zsrc[p]);
        }
        #pragma unroll
        for (int i = 0; i < 8; ++i) {
            int p = i * 4 + j;
            cvt_store4(rowp + 128 + p * 4, zdst[p]);
        }
        #pragma unroll
        for (int i = 0; i < 2; ++i) {
            int p = i * 4 + j;                  // 0..7
            cvt_store4(rowp + 256 + p * 4, emb[p]);
        }
    }
    __syncthreads();

    const int wave  = tid >> 6;         // 0..3, owns N-cols [wave*32, wave*32+32)
    const int lane  = tid & 63;
    const int quad  = lane >> 4;        // 0..3
    const int col16 = lane & 15;

    // ---- GEMM1: A[64,288](bf16) x wt1^T -> H1 [64,128] ----
    v4f zero4 = {0.f, 0.f, 0.f, 0.f};
    v4f acc[4][2];
    #pragma unroll
    for (int mt = 0; mt < 4; ++mt) { acc[mt][0] = zero4; acc[mt][1] = zero4; }

    const __bf16* w1p0 = wt1 + (size_t)(wave * 32 + col16) * DIN;
    const __bf16* w1p1 = wt1 + (size_t)(wave * 32 + 16 + col16) * DIN;

    #pragma unroll
    for (int ks = 0; ks < 9; ++ks) {
        int k0 = ks * 32 + quad * 8;
        v8bf a0 = *(const v8bf*)&sA[(0 * 16 + col16) * PADA + k0];
        v8bf a1 = *(const v8bf*)&sA[(1 * 16 + col16) * PADA + k0];
        v8bf a2 = *(const v8bf*)&sA[(2 * 16 + col16) * PADA + k0];
        v8bf a3 = *(const v8bf*)&sA[(3 * 16 + col16) * PADA + k0];
        v8bf bb0 = *(const v8bf*)&w1p0[k0];
        v8bf bb1 = *(const v8bf*)&w1p1[k0];
        acc[0][0] = __builtin_amdgcn_mfma_f32_16x16x32_bf16(a0, bb0, acc[0][0], 0, 0, 0);
        acc[1][0] = __builtin_amdgcn_mfma_f32_16x16x32_bf16(a1, bb0, acc[1][0], 0, 0, 0);
        acc[2][0] = __builtin_amdgcn_mfma_f32_16x16x32_bf16(a2, bb0, acc[2][0], 0, 0, 0);
        acc[3][0] = __builtin_amdgcn_mfma_f32_16x16x32_bf16(a3, bb0, acc[3][0], 0, 0, 0);
        acc[0][1] = __builtin_amdgcn_mfma_f32_16x16x32_bf16(a0, bb1, acc[0][1], 0, 0, 0);
        acc[1][1] = __builtin_amdgcn_mfma_f32_16x16x32_bf16(a1, bb1, acc[1][1], 0, 0, 0);
        acc[2][1] = __builtin_amdgcn_mfma_f32_16x16x32_bf16(a2, bb1, acc[2][1], 0, 0, 0);
        acc[3][1] = __builtin_amdgcn_mfma_f32_16x16x32_bf16(a3, bb1, acc[3][1], 0, 0, 0);
    }

    // epilogue: bias + relu -> sH1 (bf16, row-major [64][PAD1])
    #pragma unroll
    for (int j = 0; j < 2; ++j) {
        int n = wave * 32 + j * 16 + col16;
        float bias = sb1[n];
        #pragma unroll
        for (int mt = 0; mt < 4; ++mt) {
            #pragma unroll
            for (int r = 0; r < 4; ++r) {
                int m = mt * 16 + quad * 4 + r;
                float h = acc[mt][j][r] + bias;
                sH1[m * PAD1 + n] = (__bf16)fmaxf(h, 0.f);
            }
        }
    }
    __syncthreads();

    // ---- GEMM2: H1 [64,128] x wt2^T -> H2 [64,64]; wave owns 16 N-cols ----
    v4f acc2[4];
    #pragma unroll
    for (int mt = 0; mt < 4; ++mt) acc2[mt] = zero4;

    const __bf16* w2p = wt2 + (size_t)(wave * 16 + col16) * H1DIM;
    #pragma unroll
    for (int ks = 0; ks < 4; ++ks) {
        int k0 = ks * 32 + quad * 8;
        v8bf bb = *(const v8bf*)&w2p[k0];
        #pragma unroll
        for (int mt = 0; mt < 4; ++mt) {
            v8bf aa = *(const v8bf*)&sH1[(mt * 16 + col16) * PAD1 + k0];
            acc2[mt] = __builtin_amdgcn_mfma_f32_16x16x32_bf16(aa, bb, acc2[mt], 0, 0, 0);
        }
    }
    {
        int n = wave * 16 + col16;
        float bias = sb2[n];
        #pragma unroll
        for (int mt = 0; mt < 4; ++mt) {
            #pragma unroll
            for (int r = 0; r < 4; ++r) {
                int m = mt * 16 + quad * 4 + r;
                sH2[m * PAD2 + n] = (__bf16)fmaxf(acc2[mt][r] + bias, 0.f);
            }
        }
    }
    __syncthreads();

    // ---- GEMM3 + softplus: H2 [64,64] x W3 [64] -> out[64] (f32) ----
    {
        int row = tid >> 2;             // 0..63
        int q   = tid & 3;              // quarter of K
        float s = 0.f;
        #pragma unroll
        for (int kk = 0; kk < 16; ++kk) {
            int k = q * 16 + kk;
            s += (float)sH2[row * PAD2 + k] * sw3[k];
        }
        s += __shfl_xor(s, 1);
        s += __shfl_xor(s, 2);
        if (q == 0) {
            float x = s + sb3;
            float sp = fmaxf(x, 0.f) + log1pf(expf(-fabsf(x)));
            out[e0 + row] = sp;
        }
    }
}

extern "C" void kernel_launch(void* const* d_in, const int* in_sizes, int n_in,
                              void* d_out, int out_size, void* d_ws, size_t ws_size,
                              hipStream_t stream) {
    const float* z     = (const float*)d_in[0];
    const int*   eidx  = (const int*)d_in[1];
    const int*   btyp  = (const int*)d_in[2];
    const float* embed = (const float*)d_in[3];
    const float* W1    = (const float*)d_in[4];
    const float* b1    = (const float*)d_in[5];
    const float* W2    = (const float*)d_in[6];
    const float* b2    = (const float*)d_in[7];
    const float* W3    = (const float*)d_in[8];
    const float* b3    = (const float*)d_in[9];
    float* out = (float*)d_out;

    __bf16* wt1 = (__bf16*)d_ws;                 // bf16 [128][288]
    __bf16* wt2 = wt1 + DIN * H1DIM;             // bf16 [64][128]

    prep_kernel<<<(DIN * H1DIM + 255) / 256, 256, 0, stream>>>(W1, W2, wt1, wt2);
    fused_kernel<<<NBLK, 256, 0, stream>>>(z, eidx, btyp, embed, b1, b2, W3, b3,
                                           wt1, wt2, out);
}

// Round 4
// 244.159 us; speedup vs baseline: 1.3975x; 1.3975x over previous
//
#include <hip/hip_runtime.h>

#define E_EDGES 1000000
#define BM 64
#define NBLK (E_EDGES / BM)   // 15625
#define DIN 288
#define PADA 296              // bf16 elems; row stride 592 B; conflict-free for b128 r/w
#define H1DIM 128
#define PAD1 136
#define H2DIM 64
#define PAD2 68
#define NNODES 100000
#define LATENT 128

// d_ws element offsets (bf16)
#define WT1_OFF 0
#define WT2_OFF (DIN * H1DIM)                  // 36864
#define EMB_OFF (WT2_OFF + H1DIM * H2DIM)      // 45056
#define ZB_OFF  46080                          // 92160 B, 256B-aligned
#define WS_NEED ((size_t)(ZB_OFF + NNODES * LATENT) * 2)

typedef __bf16 v8bf __attribute__((ext_vector_type(8)));
typedef __bf16 v4bf __attribute__((ext_vector_type(4)));
typedef float  v4f  __attribute__((ext_vector_type(4)));

__device__ __forceinline__ void cvt_store4(__bf16* p, float4 v) {
    v4bf o;
    o[0] = (__bf16)v.x; o[1] = (__bf16)v.y; o[2] = (__bf16)v.z; o[3] = (__bf16)v.w;
    *(v4bf*)p = o;
}

// Transpose+convert weights; optionally convert z and embed to bf16.
__global__ void prep_kernel(const float* __restrict__ W1, const float* __restrict__ W2,
                            const float* __restrict__ z, const float* __restrict__ embed,
                            __bf16* __restrict__ ws, int do_z) {
    int i = blockIdx.x * 256 + threadIdx.x;
    if (do_z) {
        int i4 = i * 4;
        if (i4 < NNODES * LATENT) {
            float4 v = *(const float4*)(z + i4);
            cvt_store4(ws + ZB_OFF + i4, v);
        }
    }
    if (i < DIN * H1DIM) {
        int n = i / DIN, k = i - n * DIN;
        ws[WT1_OFF + i] = (__bf16)W1[k * H1DIM + n];
    }
    if (i < H1DIM * H2DIM) {
        int n = i / H1DIM, k = i - n * H1DIM;
        ws[WT2_OFF + i] = (__bf16)W2[k * H2DIM + n];
    }
    if (i < 13 * 32) ws[EMB_OFF + i] = (__bf16)embed[i];
}

template <bool ZBF16>
__global__ __launch_bounds__(256, 4) void fused_kernel(
    const float* __restrict__ z, const int* __restrict__ eidx,
    const int* __restrict__ bt, const float* __restrict__ embed,
    const float* __restrict__ b1, const float* __restrict__ b2,
    const float* __restrict__ W3, const float* __restrict__ b3,
    const __bf16* __restrict__ ws, float* __restrict__ out)
{
    // 37,888 + 1,028 = 38,916 B static LDS -> 4 blocks/CU
    __shared__ __bf16 sA[BM * PADA];
    __shared__ float sb1[H1DIM];
    __shared__ float sb2[H2DIM];
    __shared__ float sw3[H2DIM];
    __shared__ float sb3;
    // aliases inside sA (sA is dead after GEMM1's reads)
    __bf16* sH1 = sA;                  // [64][PAD1] = 8704 elems (17,408 B)
    __bf16* sH2 = sA + BM * PAD1;      // [64][PAD2] = 4352 elems ( 8,704 B)

    const __bf16* wt1  = ws + WT1_OFF;
    const __bf16* wt2  = ws + WT2_OFF;
    const __bf16* embb = ws + EMB_OFF;
    const __bf16* zb   = ws + ZB_OFF;

    const int tid = threadIdx.x;
    const int e0 = blockIdx.x * BM;

    // ---- stage biases / W3 (exact f32) ----
    if (tid < 128) {
        sb1[tid] = b1[tid];
    } else if (tid < 192) {
        sb2[tid - 128] = b2[tid - 128];
    } else {
        int k = tid - 192;
        sw3[k] = W3[k];
        if (k == 0) sb3 = b3[0];
    }

    // ---- gather A tile: 64 rows x 288 bf16 ----
    {
        const int r = tid >> 2;         // edge row 0..63
        const int j = tid & 3;          // sub-lane 0..3
        const int e = e0 + r;
        const int isrc = eidx[e];
        const int idst = eidx[E_EDGES + e];
        const int ib   = bt[e];
        __bf16* rowp = &sA[r * PADA];
        if constexpr (ZBF16) {
            const v8bf* zs = (const v8bf*)(zb + (size_t)isrc * LATENT);
            const v8bf* zd = (const v8bf*)(zb + (size_t)idst * LATENT);
            const v8bf* em = (const v8bf*)(embb + ib * 32);
            #pragma unroll
            for (int i = 0; i < 4; ++i) {
                int p = i * 4 + j;                  // 0..15
                *(v8bf*)(rowp + p * 8) = zs[p];
            }
            #pragma unroll
            for (int i = 0; i < 4; ++i) {
                int p = i * 4 + j;
                *(v8bf*)(rowp + 128 + p * 8) = zd[p];
            }
            *(v8bf*)(rowp + 256 + j * 8) = em[j];   // 4 chunks, 1/thread
        } else {
            const float4* zs = (const float4*)(z + (size_t)isrc * LATENT);
            const float4* zd = (const float4*)(z + (size_t)idst * LATENT);
            const float4* em = (const float4*)(embed + (size_t)ib * 32);
            #pragma unroll
            for (int i = 0; i < 8; ++i) { int p = i * 4 + j; cvt_store4(rowp + p * 4, zs[p]); }
            #pragma unroll
            for (int i = 0; i < 8; ++i) { int p = i * 4 + j; cvt_store4(rowp + 128 + p * 4, zd[p]); }
            #pragma unroll
            for (int i = 0; i < 2; ++i) { int p = i * 4 + j; cvt_store4(rowp + 256 + p * 4, em[p]); }
        }
    }
    __syncthreads();                    // B1: sA ready

    const int wave  = tid >> 6;
    const int lane  = tid & 63;
    const int quad  = lane >> 4;
    const int col16 = lane & 15;

    // ---- GEMM1: A[64,288] x wt1^T -> acc [64 x 32cols/wave] ----
    v4f zero4 = {0.f, 0.f, 0.f, 0.f};
    v4f acc[4][2];
    #pragma unroll
    for (int mt = 0; mt < 4; ++mt) { acc[mt][0] = zero4; acc[mt][1] = zero4; }

    const __bf16* w1p0 = wt1 + (size_t)(wave * 32 + col16) * DIN;
    const __bf16* w1p1 = wt1 + (size_t)(wave * 32 + 16 + col16) * DIN;

    #pragma unroll
    for (int ks = 0; ks < 9; ++ks) {
        int k0 = ks * 32 + quad * 8;
        v8bf a0 = *(const v8bf*)&sA[(0 * 16 + col16) * PADA + k0];
        v8bf a1 = *(const v8bf*)&sA[(1 * 16 + col16) * PADA + k0];
        v8bf a2 = *(const v8bf*)&sA[(2 * 16 + col16) * PADA + k0];
        v8bf a3 = *(const v8bf*)&sA[(3 * 16 + col16) * PADA + k0];
        v8bf bb0 = *(const v8bf*)&w1p0[k0];
        v8bf bb1 = *(const v8bf*)&w1p1[k0];
        acc[0][0] = __builtin_amdgcn_mfma_f32_16x16x32_bf16(a0, bb0, acc[0][0], 0, 0, 0);
        acc[1][0] = __builtin_amdgcn_mfma_f32_16x16x32_bf16(a1, bb0, acc[1][0], 0, 0, 0);
        acc[2][0] = __builtin_amdgcn_mfma_f32_16x16x32_bf16(a2, bb0, acc[2][0], 0, 0, 0);
        acc[3][0] = __builtin_amdgcn_mfma_f32_16x16x32_bf16(a3, bb0, acc[3][0], 0, 0, 0);
        acc[0][1] = __builtin_amdgcn_mfma_f32_16x16x32_bf16(a0, bb1, acc[0][1], 0, 0, 0);
        acc[1][1] = __builtin_amdgcn_mfma_f32_16x16x32_bf16(a1, bb1, acc[1][1], 0, 0, 0);
        acc[2][1] = __builtin_amdgcn_mfma_f32_16x16x32_bf16(a2, bb1, acc[2][1], 0, 0, 0);
        acc[3][1] = __builtin_amdgcn_mfma_f32_16x16x32_bf16(a3, bb1, acc[3][1], 0, 0, 0);
    }
    __syncthreads();                    // B2: all sA reads done (sH1 aliases sA)

    // epilogue: bias + relu -> sH1 (bf16)
    #pragma unroll
    for (int j = 0; j < 2; ++j) {
        int n = wave * 32 + j * 16 + col16;
        float bias = sb1[n];
        #pragma unroll
        for (int mt = 0; mt < 4; ++mt) {
            #pragma unroll
            for (int r = 0; r < 4; ++r) {
                int m = mt * 16 + quad * 4 + r;
                float h = acc[mt][j][r] + bias;
                sH1[m * PAD1 + n] = (__bf16)fmaxf(h, 0.f);
            }
        }
    }
    __syncthreads();                    // B3: sH1 ready

    // ---- GEMM2: H1 [64,128] x wt2^T -> H2; wave owns 16 N-cols ----
    v4f acc2[4];
    #pragma unroll
    for (int mt = 0; mt < 4; ++mt) acc2[mt] = zero4;

    const __bf16* w2p = wt2 + (size_t)(wave * 16 + col16) * H1DIM;
    #pragma unroll
    for (int ks = 0; ks < 4; ++ks) {
        int k0 = ks * 32 + quad * 8;
        v8bf bb = *(const v8bf*)&w2p[k0];
        #pragma unroll
        for (int mt = 0; mt < 4; ++mt) {
            v8bf aa = *(const v8bf*)&sH1[(mt * 16 + col16) * PAD1 + k0];
            acc2[mt] = __builtin_amdgcn_mfma_f32_16x16x32_bf16(aa, bb, acc2[mt], 0, 0, 0);
        }
    }
    {   // epilogue 2 -> sH2 (disjoint from sH1 region; no barrier needed before writes)
        int n = wave * 16 + col16;
        float bias = sb2[n];
        #pragma unroll
        for (int mt = 0; mt < 4; ++mt) {
            #pragma unroll
            for (int r = 0; r < 4; ++r) {
                int m = mt * 16 + quad * 4 + r;
                sH2[m * PAD2 + n] = (__bf16)fmaxf(acc2[mt][r] + bias, 0.f);
            }
        }
    }
    __syncthreads();                    // B4: sH2 ready

    // ---- GEMM3 + softplus ----
    {
        int row = tid >> 2;
        int q   = tid & 3;
        float s = 0.f;
        #pragma unroll
        for (int kk = 0; kk < 16; ++kk) {
            int k = q * 16 + kk;
            s += (float)sH2[row * PAD2 + k] * sw3[k];
        }
        s += __shfl_xor(s, 1);
        s += __shfl_xor(s, 2);
        if (q == 0) {
            float x = s + sb3;
            float sp = fmaxf(x, 0.f) + log1pf(expf(-fabsf(x)));
            out[e0 + row] = sp;
        }
    }
}

extern "C" void kernel_launch(void* const* d_in, const int* in_sizes, int n_in,
                              void* d_out, int out_size, void* d_ws, size_t ws_size,
                              hipStream_t stream) {
    const float* z     = (const float*)d_in[0];
    const int*   eidx  = (const int*)d_in[1];
    const int*   btyp  = (const int*)d_in[2];
    const float* embed = (const float*)d_in[3];
    const float* W1    = (const float*)d_in[4];
    const float* b1    = (const float*)d_in[5];
    const float* W2    = (const float*)d_in[6];
    const float* b2    = (const float*)d_in[7];
    const float* W3    = (const float*)d_in[8];
    const float* b3    = (const float*)d_in[9];
    float* out = (float*)d_out;
    __bf16* ws = (__bf16*)d_ws;

    bool big_ws = (ws_size >= WS_NEED);
    if (big_ws) {
        int n4 = (NNODES * LATENT / 4 + 255) / 256;  // 12500
        prep_kernel<<<n4, 256, 0, stream>>>(W1, W2, z, embed, ws, 1);
        fused_kernel<true><<<NBLK, 256, 0, stream>>>(z, eidx, btyp, embed,
                                                     b1, b2, W3, b3, ws, out);
    } else {
        prep_kernel<<<(DIN * H1DIM + 255) / 256, 256, 0, stream>>>(W1, W2, z, embed, ws, 0);
        fused_kernel<false><<<NBLK, 256, 0, stream>>>(z, eidx, btyp, embed,
                                                      b1, b2, W3, b3, ws, out);
    }
}